// Round 5
// baseline (172.140 us; speedup 1.0000x reference)
//
#include <hip/hip_runtime.h>
#include <hip/hip_bf16.h>
#include <math.h>

#define MDIM 128
#define CDIM 64
#define NKEYS 21844   // sum 4^i, i=1..7
// layer key offsets: c1=0 c2=4 c3=20 c4=84 c5=340 c6=1364 c7=5460

typedef __attribute__((ext_vector_type(8))) __bf16 bf16x8;
typedef __attribute__((ext_vector_type(4))) float f32x4;

__device__ __forceinline__ int depth_of(int n) {
  if (n < 4)    return 0;
  if (n < 20)   return 1;
  if (n < 84)   return 2;
  if (n < 340)  return 3;
  if (n < 1364) return 4;
  if (n < 5460) return 5;
  return 6;
}

// ---------------------------------------------------------------------------
// K1: keys[n][m] = relu(bk[d][m] + dot(states[n][:], Wk[d][m][:]))  -> bf16
// ---------------------------------------------------------------------------
__global__ __launch_bounds__(128) void k_keys(const float* __restrict__ states,
                                              const float* __restrict__ Wk,
                                              const float* __restrict__ bk,
                                              __hip_bfloat16* __restrict__ keys) {
  __shared__ __align__(16) float sS[4][MDIM];
  const int n0 = blockIdx.x * 4;
  const int m  = threadIdx.x;  // 0..127
  for (int idx = m; idx < 4 * MDIM; idx += 128)
    sS[idx >> 7][idx & 127] = states[(size_t)n0 * MDIM + idx];
  __syncthreads();
  const int d = depth_of(n0);
  const float4* wrow = (const float4*)(Wk + ((size_t)d * MDIM + m) * MDIM);
  float acc0 = 0.f, acc1 = 0.f, acc2 = 0.f, acc3 = 0.f;
#pragma unroll 8
  for (int kq = 0; kq < MDIM / 4; ++kq) {
    float4 w = wrow[kq];
    float4 a = *(const float4*)&sS[0][kq * 4];
    float4 b = *(const float4*)&sS[1][kq * 4];
    float4 c = *(const float4*)&sS[2][kq * 4];
    float4 e = *(const float4*)&sS[3][kq * 4];
    acc0 += w.x * a.x + w.y * a.y + w.z * a.z + w.w * a.w;
    acc1 += w.x * b.x + w.y * b.y + w.z * b.z + w.w * b.w;
    acc2 += w.x * c.x + w.y * c.y + w.z * c.z + w.w * c.w;
    acc3 += w.x * e.x + w.y * e.y + w.z * e.z + w.w * e.w;
  }
  const float bias = bk[d * MDIM + m];
  keys[(size_t)(n0 + 0) * MDIM + m] = __float2bfloat16(fmaxf(acc0 + bias, 0.f));
  keys[(size_t)(n0 + 1) * MDIM + m] = __float2bfloat16(fmaxf(acc1 + bias, 0.f));
  keys[(size_t)(n0 + 2) * MDIM + m] = __float2bfloat16(fmaxf(acc2 + bias, 0.f));
  keys[(size_t)(n0 + 3) * MDIM + m] = __float2bfloat16(fmaxf(acc3 + bias, 0.f));
}

// ---------------------------------------------------------------------------
// K2: query[b][m] = bq[m] + dot(hidden[b][:64], Wq[m][:64])  -> bf16
// ---------------------------------------------------------------------------
__global__ __launch_bounds__(128) void k_query(const float* __restrict__ hidden,
                                               const float* __restrict__ Wq,
                                               const float* __restrict__ bq,
                                               __hip_bfloat16* __restrict__ query) {
  __shared__ __align__(16) float sH[4][CDIM];
  const int b0 = blockIdx.x * 4;
  const int m  = threadIdx.x;
  for (int idx = m; idx < 4 * CDIM; idx += 128)
    sH[idx >> 6][idx & 63] = hidden[(size_t)b0 * CDIM + idx];
  __syncthreads();
  const float4* wrow = (const float4*)(Wq + (size_t)m * CDIM);
  float acc0 = 0.f, acc1 = 0.f, acc2 = 0.f, acc3 = 0.f;
#pragma unroll
  for (int kq = 0; kq < CDIM / 4; ++kq) {
    float4 w = wrow[kq];
    float4 a = *(const float4*)&sH[0][kq * 4];
    float4 b = *(const float4*)&sH[1][kq * 4];
    float4 c = *(const float4*)&sH[2][kq * 4];
    float4 e = *(const float4*)&sH[3][kq * 4];
    acc0 += w.x * a.x + w.y * a.y + w.z * a.z + w.w * a.w;
    acc1 += w.x * b.x + w.y * b.y + w.z * b.z + w.w * b.w;
    acc2 += w.x * c.x + w.y * c.y + w.z * c.z + w.w * c.w;
    acc3 += w.x * e.x + w.y * e.y + w.z * e.z + w.w * e.w;
  }
  const float bias = bq[m];
  query[(size_t)(b0 + 0) * MDIM + m] = __float2bfloat16(acc0 + bias);
  query[(size_t)(b0 + 1) * MDIM + m] = __float2bfloat16(acc1 + bias);
  query[(size_t)(b0 + 2) * MDIM + m] = __float2bfloat16(acc2 + bias);
  query[(size_t)(b0 + 3) * MDIM + m] = __float2bfloat16(acc3 + bias);
}

// ---------------------------------------------------------------------------
// K3: barrier-free register-resident subtree walker.
// Wave = one depth-5 subtree (S5) x 32 batch rows (2 b-tiles of 16).
// Block = 4 independent waves (no __syncthreads, no LDS).
// Per tile (16 keys x 16 b per b-tile), MFMA A=keys B=query:
//   D row = key = (lane>>4)*4+reg, D col = b = lane&15
//   -> lane's f32x4 = one sibling quad for one b: thread-local softmax AND
//      a store-ready float4 (4 consecutive keys) -> direct global_store.
// Parent chain in registers; child quad (u) parent = parent-tile lane
// u*16+c, reg hi -> 4 ds_bpermute + 2 cndmask.
// A-frag loads come from L2: grid is subtree-fastest so XCD = S5%8 pins
// 8 subtrees (~700KB of keys) per XCD L2.
// ---------------------------------------------------------------------------
__device__ __forceinline__ float gather_par(const f32x4 cp, int u, int lane) {
  const int src = u * 16 + (lane & 15);
  const float g0 = __shfl(cp[0], src, 64);
  const float g1 = __shfl(cp[1], src, 64);
  const float g2 = __shfl(cp[2], src, 64);
  const float g3 = __shfl(cp[3], src, 64);
  const int hi = lane >> 4;
  const float p01 = (hi & 1) ? g1 : g0;
  const float p23 = (hi & 1) ? g3 : g2;
  return (hi & 2) ? p23 : p01;
}

__device__ __forceinline__ void tile_step(const __hip_bfloat16* __restrict__ keys,
                                          int base, const bf16x8 (&qf)[2][4],
                                          const f32x4* cumPrev, int u,
                                          f32x4 (&cumOut)[2],
                                          float* __restrict__ oBase, size_t span,
                                          bool doStore, bool d1store, int lane) {
  const int c = lane & 15, hi = lane >> 4;
  const bf16x8* krow = reinterpret_cast<const bf16x8*>(keys + (size_t)(base + c) * MDIM);
  const bf16x8 af0 = krow[0 + hi];
  const bf16x8 af1 = krow[4 + hi];
  const bf16x8 af2 = krow[8 + hi];
  const bf16x8 af3 = krow[12 + hi];
#pragma unroll
  for (int bt = 0; bt < 2; ++bt) {
    f32x4 acc = {};
    acc = __builtin_amdgcn_mfma_f32_16x16x32_bf16(af0, qf[bt][0], acc, 0, 0, 0);
    acc = __builtin_amdgcn_mfma_f32_16x16x32_bf16(af1, qf[bt][1], acc, 0, 0, 0);
    acc = __builtin_amdgcn_mfma_f32_16x16x32_bf16(af2, qf[bt][2], acc, 0, 0, 0);
    acc = __builtin_amdgcn_mfma_f32_16x16x32_bf16(af3, qf[bt][3], acc, 0, 0, 0);
    const float mx  = fmaxf(fmaxf(acc[0], acc[1]), fmaxf(acc[2], acc[3]));
    const float lse = mx + __logf(__expf(acc[0] - mx) + __expf(acc[1] - mx) +
                                  __expf(acc[2] - mx) + __expf(acc[3] - mx));
    float par = 0.f;
    if (cumPrev) par = gather_par(cumPrev[bt], u, lane);
    f32x4 cm;
    cm[0] = acc[0] - lse + par;
    cm[1] = acc[1] - lse + par;
    cm[2] = acc[2] - lse + par;
    cm[3] = acc[3] - lse + par;
    cumOut[bt] = cm;
    if (doStore && (!d1store || hi == 0)) {
      float4 o;
      o.x = cm[0]; o.y = cm[1]; o.z = cm[2]; o.w = cm[3];
      *reinterpret_cast<float4*>(oBase + (size_t)(bt * 16 + c) * span + hi * 4) = o;
    }
  }
}

__global__ __launch_bounds__(256) void k_tree(const __hip_bfloat16* __restrict__ keys,
                                              const __hip_bfloat16* __restrict__ query,
                                              float* __restrict__ out, int B) {
  const int tid  = threadIdx.x;
  const int lane = tid & 63;
  const int w    = tid >> 6;
  const int c    = lane & 15, hi = lane >> 4;

  const int S5  = blockIdx.x & 63;        // depth-5 subtree (XCD = S5%8)
  const int bg  = blockIdx.x >> 6;        // batch group (128 b per block)
  const int T4  = S5 >> 2;
  const int T3  = S5 >> 4;
  const int b0w = bg * 128 + w * 32;      // wave's 32-b base

  // query B-frags for both b-tiles (held in regs for all 25 tiles)
  bf16x8 qf[2][4];
#pragma unroll
  for (int bt = 0; bt < 2; ++bt) {
    const __hip_bfloat16* qrow = query + (size_t)(b0w + bt * 16 + c) * MDIM;
#pragma unroll
    for (int kf = 0; kf < 4; ++kf)
      qf[bt][kf] = *reinterpret_cast<const bf16x8*>(qrow + kf * 32 + hi * 8);
  }

  f32x4 c1[2], c2[2], c3[2], c4[2], c5[2], c6[2], c7[2];

  // d1 (keys 0..15; quad hi==0 = the 4 real d1 nodes)
  tile_step(keys, 0, qf, nullptr, 0, c1,
            out + (size_t)b0w * 4, 4, S5 == 0, true, lane);
  // d2 (keys 4..19)
  tile_step(keys, 4, qf, c1, 0, c2,
            out + (size_t)4 * B + (size_t)b0w * 16, 16, S5 == 0, false, lane);
  // d3 (tile T3)
  tile_step(keys, 20 + 16 * T3, qf, c2, T3, c3,
            out + (size_t)20 * B + (size_t)b0w * 64 + 16 * T3, 64,
            (S5 & 15) == 0, false, lane);
  // d4 (tile T4)
  tile_step(keys, 84 + 16 * T4, qf, c3, T4 & 3, c4,
            out + (size_t)84 * B + (size_t)b0w * 256 + 16 * T4, 256,
            (S5 & 3) == 0, false, lane);
  // d5 (tile S5)
  tile_step(keys, 340 + 16 * S5, qf, c4, S5 & 3, c5,
            out + (size_t)340 * B + (size_t)b0w * 1024 + 16 * S5, 1024,
            true, false, lane);

#pragma unroll
  for (int u5 = 0; u5 < 4; ++u5) {
    const int T6 = 4 * S5 + u5;
    tile_step(keys, 1364 + 16 * T6, qf, c5, u5, c6,
              out + (size_t)1364 * B + (size_t)b0w * 4096 + 16 * T6, 4096,
              true, false, lane);
#pragma unroll
    for (int u6 = 0; u6 < 4; ++u6) {
      const int T7 = 4 * T6 + u6;
      tile_step(keys, 5460 + 16 * T7, qf, c6, u6, c7,
                out + (size_t)5460 * B + (size_t)b0w * 16384 + 16 * T7, 16384,
                true, false, lane);
    }
  }
}

// ---------------------------------------------------------------------------
extern "C" void kernel_launch(void* const* d_in, const int* in_sizes, int n_in,
                              void* d_out, int out_size, void* d_ws, size_t ws_size,
                              hipStream_t stream) {
  const float* hidden = (const float*)d_in[0];
  const float* Wq     = (const float*)d_in[1];
  const float* bq     = (const float*)d_in[2];
  const float* states = (const float*)d_in[3];
  const float* Wk     = (const float*)d_in[4];
  const float* bk     = (const float*)d_in[5];
  float* out = (float*)d_out;
  const int B = in_sizes[0] / CDIM;  // 4096

  __hip_bfloat16* keys  = (__hip_bfloat16*)d_ws;        // NKEYS*128 bf16 = 5.6 MB
  __hip_bfloat16* query = keys + (size_t)NKEYS * MDIM;  // B*128 bf16 = 1 MB

  k_keys<<<NKEYS / 4, 128, 0, stream>>>(states, Wk, bk, keys);
  k_query<<<B / 4, 128, 0, stream>>>(hidden, Wq, bq, query);

  // grid: subtree-fastest (XCD pinning): 64 subtrees x B/128 batch groups
  k_tree<<<(B / 128) * 64, 256, 0, stream>>>(keys, query, out, B);
}

// Round 6
// 148.281 us; speedup vs baseline: 1.1609x; 1.1609x over previous
//
#include <hip/hip_runtime.h>
#include <hip/hip_bf16.h>
#include <math.h>

#define MDIM 128
#define CDIM 64
#define NKEYS 21844   // sum 4^i, i=1..7
// layer key offsets: c1=0 c2=4 c3=20 c4=84 c5=340 c6=1364 c7=5460

typedef __attribute__((ext_vector_type(8))) __bf16 bf16x8;
typedef __attribute__((ext_vector_type(4))) float f32x4;

__device__ __forceinline__ int depth_of(int n) {
  if (n < 4)    return 0;
  if (n < 20)   return 1;
  if (n < 84)   return 2;
  if (n < 340)  return 3;
  if (n < 1364) return 4;
  if (n < 5460) return 5;
  return 6;
}

// ---------------------------------------------------------------------------
// K1: keys[n][m] = relu(bk[d][m] + dot(states[n][:], Wk[d][m][:]))  -> bf16
// ---------------------------------------------------------------------------
__global__ __launch_bounds__(128) void k_keys(const float* __restrict__ states,
                                              const float* __restrict__ Wk,
                                              const float* __restrict__ bk,
                                              __hip_bfloat16* __restrict__ keys) {
  __shared__ __align__(16) float sS[4][MDIM];
  const int n0 = blockIdx.x * 4;
  const int m  = threadIdx.x;  // 0..127
  for (int idx = m; idx < 4 * MDIM; idx += 128)
    sS[idx >> 7][idx & 127] = states[(size_t)n0 * MDIM + idx];
  __syncthreads();
  const int d = depth_of(n0);
  const float4* wrow = (const float4*)(Wk + ((size_t)d * MDIM + m) * MDIM);
  float acc0 = 0.f, acc1 = 0.f, acc2 = 0.f, acc3 = 0.f;
#pragma unroll 8
  for (int kq = 0; kq < MDIM / 4; ++kq) {
    float4 w = wrow[kq];
    float4 a = *(const float4*)&sS[0][kq * 4];
    float4 b = *(const float4*)&sS[1][kq * 4];
    float4 c = *(const float4*)&sS[2][kq * 4];
    float4 e = *(const float4*)&sS[3][kq * 4];
    acc0 += w.x * a.x + w.y * a.y + w.z * a.z + w.w * a.w;
    acc1 += w.x * b.x + w.y * b.y + w.z * b.z + w.w * b.w;
    acc2 += w.x * c.x + w.y * c.y + w.z * c.z + w.w * c.w;
    acc3 += w.x * e.x + w.y * e.y + w.z * e.z + w.w * e.w;
  }
  const float bias = bk[d * MDIM + m];
  keys[(size_t)(n0 + 0) * MDIM + m] = __float2bfloat16(fmaxf(acc0 + bias, 0.f));
  keys[(size_t)(n0 + 1) * MDIM + m] = __float2bfloat16(fmaxf(acc1 + bias, 0.f));
  keys[(size_t)(n0 + 2) * MDIM + m] = __float2bfloat16(fmaxf(acc2 + bias, 0.f));
  keys[(size_t)(n0 + 3) * MDIM + m] = __float2bfloat16(fmaxf(acc3 + bias, 0.f));
}

// ---------------------------------------------------------------------------
// K2: query[b][m] = bq[m] + dot(hidden[b][:64], Wq[m][:64])  -> bf16
// ---------------------------------------------------------------------------
__global__ __launch_bounds__(128) void k_query(const float* __restrict__ hidden,
                                               const float* __restrict__ Wq,
                                               const float* __restrict__ bq,
                                               __hip_bfloat16* __restrict__ query) {
  __shared__ __align__(16) float sH[4][CDIM];
  const int b0 = blockIdx.x * 4;
  const int m  = threadIdx.x;
  for (int idx = m; idx < 4 * CDIM; idx += 128)
    sH[idx >> 6][idx & 63] = hidden[(size_t)b0 * CDIM + idx];
  __syncthreads();
  const float4* wrow = (const float4*)(Wq + (size_t)m * CDIM);
  float acc0 = 0.f, acc1 = 0.f, acc2 = 0.f, acc3 = 0.f;
#pragma unroll
  for (int kq = 0; kq < CDIM / 4; ++kq) {
    float4 w = wrow[kq];
    float4 a = *(const float4*)&sH[0][kq * 4];
    float4 b = *(const float4*)&sH[1][kq * 4];
    float4 c = *(const float4*)&sH[2][kq * 4];
    float4 e = *(const float4*)&sH[3][kq * 4];
    acc0 += w.x * a.x + w.y * a.y + w.z * a.z + w.w * a.w;
    acc1 += w.x * b.x + w.y * b.y + w.z * b.z + w.w * b.w;
    acc2 += w.x * c.x + w.y * c.y + w.z * c.z + w.w * c.w;
    acc3 += w.x * e.x + w.y * e.y + w.z * e.z + w.w * e.w;
  }
  const float bias = bq[m];
  query[(size_t)(b0 + 0) * MDIM + m] = __float2bfloat16(acc0 + bias);
  query[(size_t)(b0 + 1) * MDIM + m] = __float2bfloat16(acc1 + bias);
  query[(size_t)(b0 + 2) * MDIM + m] = __float2bfloat16(acc2 + bias);
  query[(size_t)(b0 + 3) * MDIM + m] = __float2bfloat16(acc3 + bias);
}

// ---------------------------------------------------------------------------
// K3: subtree walker, v6.
// Block = 4 waves x 128 b x one depth-5 subtree. Keys staged in shared LDS
// (swizzled, double-buffered, reg-staged with single barrier per tile: the
// global latency hides under compute). Cum chain in registers (shuffle
// parent gather). d7 output (75% of bytes) goes through a per-wave LDS
// transpose buffer [32 b][64 keys] (stride 68: bank-uniform), flushed per
// u5-group as 8 stores of 4x256B segments -> 1KB-per-row write bursts.
// ---------------------------------------------------------------------------
#define D7STR 68   // padded row stride (floats)

__device__ __forceinline__ float gather_par(const f32x4 cp, int u, int lane) {
  const int src = u * 16 + (lane & 15);
  const float g0 = __shfl(cp[0], src, 64);
  const float g1 = __shfl(cp[1], src, 64);
  const float g2 = __shfl(cp[2], src, 64);
  const float g3 = __shfl(cp[3], src, 64);
  const int hi = lane >> 4;
  const float p01 = (hi & 1) ? g1 : g0;
  const float p23 = (hi & 1) ? g3 : g2;
  return (hi & 2) ? p23 : p01;
}

__device__ __forceinline__ void tile_step(
    const char* __restrict__ gsrc, char* __restrict__ sdst0,
    const char* __restrict__ sKB, int& sbuf, int nextBase,
    const bf16x8 (&qf)[2][4], const f32x4* cumPrev, int u,
    f32x4 (&cumOut)[2], float* __restrict__ oBase, size_t span,
    bool doStore, bool d1store, float* __restrict__ d7dst, int lane) {
  const int c = lane & 15, hi = lane >> 4;

  // stage next tile into regs (latency hides under compute below)
  float4 stg;
  if (nextBase >= 0)
    stg = *reinterpret_cast<const float4*>(gsrc + (size_t)nextBase * 256);

  // A-frags from swizzled LDS tile
  const char* kt = sKB + sbuf * 4096;
  bf16x8 af[4];
#pragma unroll
  for (int kf = 0; kf < 4; ++kf)
    af[kf] = *reinterpret_cast<const bf16x8*>(
        kt + c * 256 + (((kf * 4 + hi) ^ (c & 7)) << 4));

#pragma unroll
  for (int bt = 0; bt < 2; ++bt) {
    f32x4 acc = {};
    acc = __builtin_amdgcn_mfma_f32_16x16x32_bf16(af[0], qf[bt][0], acc, 0, 0, 0);
    acc = __builtin_amdgcn_mfma_f32_16x16x32_bf16(af[1], qf[bt][1], acc, 0, 0, 0);
    acc = __builtin_amdgcn_mfma_f32_16x16x32_bf16(af[2], qf[bt][2], acc, 0, 0, 0);
    acc = __builtin_amdgcn_mfma_f32_16x16x32_bf16(af[3], qf[bt][3], acc, 0, 0, 0);
    const float mx  = fmaxf(fmaxf(acc[0], acc[1]), fmaxf(acc[2], acc[3]));
    const float lse = mx + __logf(__expf(acc[0] - mx) + __expf(acc[1] - mx) +
                                  __expf(acc[2] - mx) + __expf(acc[3] - mx));
    float par = 0.f;
    if (cumPrev) par = gather_par(cumPrev[bt], u, lane);
    f32x4 cm;
    cm[0] = acc[0] - lse + par;
    cm[1] = acc[1] - lse + par;
    cm[2] = acc[2] - lse + par;
    cm[3] = acc[3] - lse + par;
    cumOut[bt] = cm;
    if (d7dst) {
      *reinterpret_cast<f32x4*>(d7dst + (bt * 16 + c) * D7STR) = cm;
    } else if (doStore && (!d1store || hi == 0)) {
      float4 o;
      o.x = cm[0]; o.y = cm[1]; o.z = cm[2]; o.w = cm[3];
      *reinterpret_cast<float4*>(oBase + (size_t)(bt * 16 + c) * span + hi * 4) = o;
    }
  }

  // publish staged tile to the other buffer, then single barrier
  if (nextBase >= 0)
    *reinterpret_cast<float4*>(sdst0 + (sbuf ^ 1) * 4096) = stg;
  __syncthreads();
  sbuf ^= 1;
}

__global__ __launch_bounds__(256) void k_tree(const __hip_bfloat16* __restrict__ keys,
                                              const __hip_bfloat16* __restrict__ query,
                                              float* __restrict__ out, int B) {
  __shared__ __align__(16) float sKeys[2][1024];      // 2 x 4KB shared key tiles
  __shared__ __align__(16) float sD7[4][32 * D7STR];  // per-wave d7 transpose buf

  const int tid  = threadIdx.x;
  const int lane = tid & 63;
  const int w    = tid >> 6;
  const int c    = lane & 15, hi = lane >> 4;

  const int S5  = blockIdx.x & 63;        // depth-5 subtree (XCD = S5%8)
  const int bg  = blockIdx.x >> 6;        // batch group (128 b per block)
  const int T4  = S5 >> 2;
  const int T3  = S5 >> 4;
  const int b0w = bg * 128 + w * 32;      // wave's 32-b base

  // staging mapping: thread -> (row, chunk); LDS[r][j] = G[r][j ^ (r&7)]
  const int srow = tid >> 4, schunk = tid & 15;
  const char* gsrc = reinterpret_cast<const char*>(keys) + (size_t)srow * 256 + schunk * 16;
  char* sdst0 = reinterpret_cast<char*>(&sKeys[0][0]) + srow * 256 +
                ((schunk ^ (srow & 7)) << 4);
  const char* sKB = reinterpret_cast<const char*>(&sKeys[0][0]);

  // query B-frags for both b-tiles (held in regs for all 25 tiles)
  bf16x8 qf[2][4];
#pragma unroll
  for (int bt = 0; bt < 2; ++bt) {
    const __hip_bfloat16* qrow = query + (size_t)(b0w + bt * 16 + c) * MDIM;
#pragma unroll
    for (int kf = 0; kf < 4; ++kf)
      qf[bt][kf] = *reinterpret_cast<const bf16x8*>(qrow + kf * 32 + hi * 8);
  }

  // prologue: stage tile 0 (key base 0)
  *reinterpret_cast<float4*>(sdst0) = *reinterpret_cast<const float4*>(gsrc);
  __syncthreads();
  int sbuf = 0;

  f32x4 c1[2], c2[2], c3[2], c4[2], c5[2], c6[2], c7[2];
  float* d7w  = &sD7[w][0];
  float* out7 = out + (size_t)5460 * B + (size_t)b0w * 16384;

  // d1 (keys 0..15; quad hi==0 = real d1 nodes)
  tile_step(gsrc, sdst0, sKB, sbuf, 4, qf, nullptr, 0, c1,
            out + (size_t)b0w * 4, 4, S5 == 0, true, nullptr, lane);
  // d2 (keys 4..19)
  tile_step(gsrc, sdst0, sKB, sbuf, 20 + 16 * T3, qf, c1, 0, c2,
            out + (size_t)4 * B + (size_t)b0w * 16, 16, S5 == 0, false, nullptr, lane);
  // d3 (tile T3)
  tile_step(gsrc, sdst0, sKB, sbuf, 84 + 16 * T4, qf, c2, T3, c3,
            out + (size_t)20 * B + (size_t)b0w * 64 + 16 * T3, 64,
            (S5 & 15) == 0, false, nullptr, lane);
  // d4 (tile T4)
  tile_step(gsrc, sdst0, sKB, sbuf, 340 + 16 * S5, qf, c3, T4 & 3, c4,
            out + (size_t)84 * B + (size_t)b0w * 256 + 16 * T4, 256,
            (S5 & 3) == 0, false, nullptr, lane);
  // d5 (tile S5); next = first d6 tile
  tile_step(gsrc, sdst0, sKB, sbuf, 1364 + 16 * (4 * S5), qf, c4, S5 & 3, c5,
            out + (size_t)340 * B + (size_t)b0w * 1024 + 16 * S5, 1024,
            true, false, nullptr, lane);

#pragma unroll
  for (int u5 = 0; u5 < 4; ++u5) {
    const int T6 = 4 * S5 + u5;
    // d6 tile T6; next = its first d7 child
    tile_step(gsrc, sdst0, sKB, sbuf, 5460 + 16 * (4 * T6), qf, c5, u5, c6,
              out + (size_t)1364 * B + (size_t)b0w * 4096 + 16 * T6, 4096,
              true, false, nullptr, lane);
#pragma unroll
    for (int u6 = 0; u6 < 4; ++u6) {
      const int T7 = 4 * T6 + u6;
      int nb;
      if (u6 < 3)      nb = 5460 + 16 * (T7 + 1);
      else if (u5 < 3) nb = 1364 + 16 * (4 * S5 + u5 + 1);
      else             nb = -1;
      tile_step(gsrc, sdst0, sKB, sbuf, nb, qf, c6, u6, c7,
                nullptr, 0, false, false, d7w + u6 * 16 + hi * 4, lane);
    }
    // flush d7 u5-group: 32 b-rows x 64 keys; 8 instrs x 4 x 256B segments
#pragma unroll
    for (int j = 0; j < 8; ++j) {
      const int r = j * 4 + hi;
      f32x4 v = *reinterpret_cast<const f32x4*>(d7w + r * D7STR + c * 4);
      float4 o;
      o.x = v[0]; o.y = v[1]; o.z = v[2]; o.w = v[3];
      *reinterpret_cast<float4*>(out7 + (size_t)r * 16384 + 64 * T6 + c * 4) = o;
    }
  }
}

// ---------------------------------------------------------------------------
extern "C" void kernel_launch(void* const* d_in, const int* in_sizes, int n_in,
                              void* d_out, int out_size, void* d_ws, size_t ws_size,
                              hipStream_t stream) {
  const float* hidden = (const float*)d_in[0];
  const float* Wq     = (const float*)d_in[1];
  const float* bq     = (const float*)d_in[2];
  const float* states = (const float*)d_in[3];
  const float* Wk     = (const float*)d_in[4];
  const float* bk     = (const float*)d_in[5];
  float* out = (float*)d_out;
  const int B = in_sizes[0] / CDIM;  // 4096

  __hip_bfloat16* keys  = (__hip_bfloat16*)d_ws;        // NKEYS*128 bf16 = 5.6 MB
  __hip_bfloat16* query = keys + (size_t)NKEYS * MDIM;  // B*128 bf16 = 1 MB

  k_keys<<<NKEYS / 4, 128, 0, stream>>>(states, Wk, bk, keys);
  k_query<<<B / 4, 128, 0, stream>>>(hidden, Wq, bq, query);

  // grid: subtree-fastest (XCD pinning): 64 subtrees x B/128 batch groups
  k_tree<<<(B / 128) * 64, 256, 0, stream>>>(keys, query, out, B);
}